// Round 1
// baseline (66.339 us; speedup 1.0000x reference)
//
#include <hip/hip_runtime.h>
#include <hip/hip_bf16.h>

#define HIDDEN 512
#define SEQ 256
#define GROUPS 16
#define BLOCKT 16

// One block: one b, 16 consecutive h. 256 threads: tid = h_local*16 + t.
// Each thread: load 16 contiguous x floats (one 16-chunk), multiply by the
// 16x16 per-h matrix (staged in LDS), store 16 contiguous y floats.
__global__ __launch_bounds__(256) void LocalMixer_47579647705675_kernel(
    const float* __restrict__ x, const float* __restrict__ W,
    float* __restrict__ y) {
  __shared__ float Ws[16 * 256];  // 16 h * (16 o * 16 g) = 16 KiB

  const int blk = blockIdx.x;
  const int b  = blk >> 5;          // 32 h-tiles per b
  const int h0 = (blk & 31) << 4;   // first h of this tile

  // Stage W[h0..h0+15] into LDS: 4096 floats = 1024 float4, 256 threads x 4.
  {
    const float4* Wg = reinterpret_cast<const float4*>(W + (size_t)h0 * 256);
    float4* Wl = reinterpret_cast<float4*>(Ws);
#pragma unroll
    for (int i = 0; i < 4; ++i)
      Wl[i * 256 + threadIdx.x] = Wg[i * 256 + threadIdx.x];
  }
  __syncthreads();

  const int hl = threadIdx.x >> 4;   // h within tile
  const int t  = threadIdx.x & 15;   // 16-chunk index

  const size_t base = ((size_t)b * HIDDEN + h0 + hl) * SEQ + (size_t)t * GROUPS;

  // Load this thread's 16 x values (64 contiguous bytes).
  float xr[16];
  {
    float4* xr4 = reinterpret_cast<float4*>(xr);
    const float4* xp = reinterpret_cast<const float4*>(x + base);
#pragma unroll
    for (int j = 0; j < 4; ++j) xr4[j] = xp[j];
  }

  // y[o] = sum_g xr[g] * W[h][o][g]
  float yr[16];
  const float4* Wrow = reinterpret_cast<const float4*>(Ws + hl * 256);
#pragma unroll
  for (int o = 0; o < 16; ++o) {
    const float4 w0 = Wrow[4 * o + 0];
    const float4 w1 = Wrow[4 * o + 1];
    const float4 w2 = Wrow[4 * o + 2];
    const float4 w3 = Wrow[4 * o + 3];
    float a;
    a = xr[0] * w0.x;
    a = fmaf(xr[1],  w0.y, a);
    a = fmaf(xr[2],  w0.z, a);
    a = fmaf(xr[3],  w0.w, a);
    a = fmaf(xr[4],  w1.x, a);
    a = fmaf(xr[5],  w1.y, a);
    a = fmaf(xr[6],  w1.z, a);
    a = fmaf(xr[7],  w1.w, a);
    a = fmaf(xr[8],  w2.x, a);
    a = fmaf(xr[9],  w2.y, a);
    a = fmaf(xr[10], w2.z, a);
    a = fmaf(xr[11], w2.w, a);
    a = fmaf(xr[12], w3.x, a);
    a = fmaf(xr[13], w3.y, a);
    a = fmaf(xr[14], w3.z, a);
    a = fmaf(xr[15], w3.w, a);
    yr[o] = a;
  }

  // Store 16 contiguous y values.
  {
    const float4* yr4 = reinterpret_cast<const float4*>(yr);
    float4* yp = reinterpret_cast<float4*>(y + base);
#pragma unroll
    for (int j = 0; j < 4; ++j) yp[j] = yr4[j];
  }
}

extern "C" void kernel_launch(void* const* d_in, const int* in_sizes, int n_in,
                              void* d_out, int out_size, void* d_ws, size_t ws_size,
                              hipStream_t stream) {
  const float* x = (const float*)d_in[0];
  const float* W = (const float*)d_in[1];
  float* y = (float*)d_out;

  const int B = in_sizes[0] / (HIDDEN * SEQ);  // 256
  const int grid = B * (HIDDEN / 16);          // 8192 blocks
  LocalMixer_47579647705675_kernel<<<grid, 256, 0, stream>>>(x, W, y);
}